// Round 6
// baseline (224.396 us; speedup 1.0000x reference)
//
#include <hip/hip_runtime.h>
#include <float.h>

#define N_VOX 32768
#define N_CODES 8192
#define DIM 64

// output float offsets (flat, in return order)
#define Q_OFF 0
#define VQ_OFF (N_VOX * DIM)      // 2097152
#define CM_OFF (VQ_OFF + 1)
#define IDX_OFF (VQ_OFF + 2)

// workspace float offsets
#define WS_ACC 0
#define WS_CNT 1                      // int: blocks-done counter
#define WS_ESQH 64                    // 8192 floats: -||e||^2 / 2  (NEGATED)
#define WS_IDX (WS_ESQH + N_CODES)    // (unused, layout kept)
#define WS_EHI (WS_IDX + N_VOX)       // codebook hi-plane f16 (1 MB, swizzled)
#define WS_ELO (WS_EHI + N_CODES * DIM / 2)  // lo-plane f16 (1 MB)

typedef _Float16 half8 __attribute__((ext_vector_type(8)));
typedef float floatx4 __attribute__((ext_vector_type(4)));

// async global->LDS; lds dest is wave-uniform base (+lane*size), global src per-lane
__device__ inline void gld16(const void* g, void* l) {
  __builtin_amdgcn_global_load_lds(
      (const __attribute__((address_space(1))) unsigned int*)g,
      (__attribute__((address_space(3))) unsigned int*)l, 16, 0, 0);
}
__device__ inline void gld4(const void* g, void* l) {
  __builtin_amdgcn_global_load_lds(
      (const __attribute__((address_space(1))) unsigned int*)g,
      (__attribute__((address_space(3))) unsigned int*)l, 4, 0, 0);
}

__device__ __forceinline__ floatx4 mfma16(half8 a, half8 b, floatx4 c) {
  return __builtin_amdgcn_mfma_f32_16x16x32_f16(a, b, c, 0, 0, 0);
}

// ---------------------------------------------------------------- k_cvt
// Pre-convert codebook to hi/lo f16 planes (XOR-swizzled 16B chunks) +
// NEGATED esq/2 (folds into MFMA C-init with zero VALU in the hot loop).
__global__ __launch_bounds__(256) void k_cvt(const float* __restrict__ e,
                                             float* __restrict__ ws) {
  int gid = blockIdx.x * 256 + threadIdx.x;
  if (gid == 0) {                            // ws is poisoned each run
    ws[WS_ACC] = 0.f;
    ((int*)ws)[WS_CNT] = 0;
  }
  int row = gid >> 3, c = gid & 7;
  const float* src = e + (size_t)row * DIM + c * 8;
  float4 a = *(const float4*)src;
  float4 b = *(const float4*)(src + 4);
  float x[8] = {a.x, a.y, a.z, a.w, b.x, b.y, b.z, b.w};
  float s = 0.f;
  half8 hv, lv;
  #pragma unroll
  for (int j = 0; j < 8; ++j) {
    s += x[j] * x[j];                        // esq in full fp32 from originals
    _Float16 h = (_Float16)x[j];
    hv[j] = h;
    lv[j] = (_Float16)(x[j] - (float)h);
  }
  s += __shfl_xor(s, 1); s += __shfl_xor(s, 2); s += __shfl_xor(s, 4);
  if (c == 0) ws[WS_ESQH + row] = -0.5f * s;
  int p = (c + row) & 7;                     // rotate swizzle within row
  ((half8*)(ws + WS_EHI))[row * 8 + p] = hv;
  ((half8*)(ws + WS_ELO))[row * 8 + p] = lv;
}

// ---------------------------------------------------------------- k_argmin
// OCCUPANCY round: 512-thread blocks (8 waves), same 512-block grid, same
// per-block work (64 voxels x all 8192 codes, 128-code double-buffered
// swizzled tiles, 64 barrier rounds, fused epilogue). Each wave owns a
// disjoint 16-code slice of the tile (no duplicate B reads; M=4, 24 MFMA +
// 4 ds_read_b128 per wave per tile). 69 KB LDS -> 2 blocks/CU -> 16
// waves/CU = 4 waves/SIMD: doubles the latency-interleave depth that every
// previous round (8 waves/CU) lacked -- the single variable under test.
// Score s = dot - esq/2 (maximize); -esq/2 folded into MFMA C-init.
// dot via 3-term f16 split (hh + hl + lh), two independent 3-chains.
__global__ __launch_bounds__(512, 4) void k_argmin(const float* __restrict__ z,
                                                   const float* __restrict__ e,
                                                   float* __restrict__ ws,
                                                   float* __restrict__ out) {
  __shared__ __align__(16) _Float16 sBhi[2][128 * 64];   // 32 KB
  __shared__ __align__(16) _Float16 sBlo[2][128 * 64];   // 32 KB
  __shared__ float sEsq[2][128];                          // 1 KB
  __shared__ float sMval[8][64];                          // 2 KB
  __shared__ int   sMidx[8][64];                          // 2 KB
  __shared__ int   sWin[64];
  __shared__ float sWsum[8];

  const int tid  = threadIdx.x;
  const int lane = tid & 63;
  const int wave = tid >> 6;       // which 16-code slice of the 128-tile
  const int n16  = lane & 15;
  const int quad = lane >> 4;
  const int vb = blockIdx.x * 64;

  const char* ehi_b = (const char*)(ws + WS_EHI);
  const char* elo_b = (const char*)(ws + WS_ELO);
  const char* esq_b = (const char*)(ws + WS_ESQH);

  // A fragments: ALL 64 voxels x 64 dims, hi/lo. A[m][kc]: row=n16, k=quad*8+j
  half8 ahi[4][2], alo[4][2];
  #pragma unroll
  for (int m = 0; m < 4; ++m)
    #pragma unroll
    for (int kc = 0; kc < 2; ++kc) {
      const float* src = z + (size_t)(vb + m * 16 + n16) * DIM
                       + kc * 32 + quad * 8;
      float4 a = *(const float4*)src;
      float4 b = *(const float4*)(src + 4);
      float x[8] = {a.x, a.y, a.z, a.w, b.x, b.y, b.z, b.w};
      #pragma unroll
      for (int j = 0; j < 8; ++j) {
        _Float16 h = (_Float16)x[j];
        ahi[m][kc][j] = h;
        alo[m][kc][j] = (_Float16)(x[j] - (float)h);
      }
    }

  float bmax[4][4]; int bidx[4][4];
  #pragma unroll
  for (int m = 0; m < 4; ++m)
    #pragma unroll
    for (int r = 0; r < 4; ++r) { bmax[m][r] = -FLT_MAX; bidx[m][r] = 0; }

  // swizzled chunk offsets (f16 units) for this lane's B-row reads
  // (LDS row & 7 == n16 & 7, matching k_cvt's p = (chunk + row) & 7)
  const int s0 = ((quad + n16) & 7) * 8;          // kc=0 chunk
  const int s1 = ((quad + 4 + n16) & 7) * 8;      // kc=1 chunk

  // stage one 128-code tile (hi+lo planes + esq) into buffer buf
  // 16 KB/plane staged as 16 x 1KB chunks; wave w stages chunks {2w, 2w+1}
  auto stage = [&](int buf, int ct) {
    const size_t cbb = (size_t)ct * 128 * 128;    // bytes per plane-tile
    #pragma unroll
    for (int r = 0; r < 2; ++r) {
      int off = (wave * 2 + r) * 1024;            // wave-uniform LDS base
      gld16(ehi_b + cbb + off + lane * 16, (char*)sBhi[buf] + off);
      gld16(elo_b + cbb + off + lane * 16, (char*)sBlo[buf] + off);
    }
    if (wave == 0) {
      gld4(esq_b + (size_t)ct * 512 + lane * 4, (char*)sEsq[buf]);
      gld4(esq_b + (size_t)ct * 512 + 256 + lane * 4, (char*)sEsq[buf] + 256);
    }
  };

  stage(0, 0);
  __syncthreads();

  for (int ct = 0; ct < 64; ++ct) {
    const int cur = ct & 1;
    if (ct < 63) stage(cur ^ 1, ct + 1);          // prefetch next tile (async)

    const _Float16* bhiP = sBhi[cur];
    const _Float16* bloP = sBlo[cur];
    const float*    esqP = sEsq[cur];

    const int row = wave * 16 + n16;              // this wave's code row
    half8 bh0 = *(const half8*)&bhiP[row * 64 + s0];
    half8 bh1 = *(const half8*)&bhiP[row * 64 + s1];
    half8 bl0 = *(const half8*)&bloP[row * 64 + s0];
    half8 bl1 = *(const half8*)&bloP[row * 64 + s1];
    float nh = esqP[row];                         // -esq/2 for this code
    int code = ct * 128 + row;

    __builtin_amdgcn_s_setprio(1);
    #pragma unroll
    for (int m = 0; m < 4; ++m) {
      floatx4 acc0 = {nh, nh, nh, nh};
      floatx4 acc1 = {0.f, 0.f, 0.f, 0.f};
      // two independent 3-chains (hh0,hl0,lh0 | hh1,hl1,lh1)
      acc0 = mfma16(ahi[m][0], bh0, acc0);
      acc1 = mfma16(ahi[m][1], bh1, acc1);
      acc0 = mfma16(ahi[m][0], bl0, acc0);
      acc1 = mfma16(ahi[m][1], bl1, acc1);
      acc0 = mfma16(alo[m][0], bh0, acc0);
      acc1 = mfma16(alo[m][1], bh1, acc1);
      // C layout: col = lane&15 (this lane's code), row = quad*4 + r (voxel)
      #pragma unroll
      for (int r = 0; r < 4; ++r) {
        float tv = acc0[r] + acc1[r];
        if (tv > bmax[m][r]) { bmax[m][r] = tv; bidx[m][r] = code; }
      }
    }
    __builtin_amdgcn_s_setprio(0);
    __syncthreads();     // staging for ct+1 done + all reads of cur finished
  }

  // reduce across the 16 lanes (n16 = code col) holding each voxel's partials
  #pragma unroll
  for (int m = 0; m < 4; ++m)
    #pragma unroll
    for (int r = 0; r < 4; ++r) {
      float v = bmax[m][r]; int i = bidx[m][r];
      #pragma unroll
      for (int off = 1; off < 16; off <<= 1) {
        float ov = __shfl_xor(v, off);
        int   oi = __shfl_xor(i, off);
        if (ov > v || (ov == v && oi < i)) { v = ov; i = oi; }
      }
      if (n16 == 0) {
        sMval[wave][m * 16 + quad * 4 + r] = v;
        sMidx[wave][m * 16 + quad * 4 + r] = i;
      }
    }
  __syncthreads();

  // merge the eight code-slices, publish winner index
  if (tid < 64) {
    float v = sMval[0][tid]; int i = sMidx[0][tid];
    #pragma unroll
    for (int q = 1; q < 8; ++q) {
      float ov = sMval[q][tid]; int oi = sMidx[q][tid];
      if (ov > v || (ov == v && oi < i)) { v = ov; i = oi; }
    }
    sWin[tid] = i;
    out[IDX_OFF + vb + tid] = (float)i;
  }
  __syncthreads();

  // fused k_out: gather quantized rows (exact fp32), accumulate (z-q)^2
  {
    const int vox = tid >> 3;                 // 64 voxels x 8 threads
    const int dc = (tid & 7) * 8;             // 8 floats per thread
    const int gi = sWin[vox];
    const float* er = e + (size_t)gi * DIM + dc;
    const float* zr = z + (size_t)(vb + vox) * DIM + dc;
    float* qr = out + Q_OFF + (size_t)(vb + vox) * DIM + dc;
    float local = 0.f;
    #pragma unroll
    for (int j = 0; j < 2; ++j) {
      float4 e4 = *(const float4*)(er + j * 4);
      float4 z4 = *(const float4*)(zr + j * 4);
      *(float4*)(qr + j * 4) = e4;
      float dx = z4.x - e4.x, dy = z4.y - e4.y, dz = z4.z - e4.z, dw = z4.w - e4.w;
      local += dx * dx + dy * dy + dz * dz + dw * dw;
    }
    #pragma unroll
    for (int off = 32; off; off >>= 1) local += __shfl_xor(local, off);
    if ((tid & 63) == 0) sWsum[wave] = local;
    __syncthreads();
    if (tid == 0) {
      float bs = 0.f;
      #pragma unroll
      for (int q = 0; q < 8; ++q) bs += sWsum[q];
      atomicAdd(ws + WS_ACC, bs);            // device-scope
      __threadfence();
      int done = atomicAdd((int*)ws + WS_CNT, 1);
      if (done == (int)gridDim.x - 1) {      // last block: finalize scalars
        float s = atomicAdd(ws + WS_ACC, 0.f);   // atomic read (coherent)
        float mv = s * (1.0f / (float)(N_VOX * DIM));
        out[VQ_OFF] = mv;   // vq_loss
        out[CM_OFF] = mv;   // commitment_loss (identical forward value)
      }
    }
  }
}

// ----------------------------------------------------------------
extern "C" void kernel_launch(void* const* d_in, const int* in_sizes, int n_in,
                              void* d_out, int out_size, void* d_ws, size_t ws_size,
                              hipStream_t stream) {
  const float* z = (const float*)d_in[0];
  const float* e = (const float*)d_in[1];
  float* out = (float*)d_out;
  float* ws = (float*)d_ws;

  k_cvt<<<(N_CODES * 8) / 256, 256, 0, stream>>>(e, ws);
  k_argmin<<<N_VOX / 64, 512, 0, stream>>>(z, e, ws, out);
}

// Round 7
// 189.607 us; speedup vs baseline: 1.1835x; 1.1835x over previous
//
#include <hip/hip_runtime.h>
#include <float.h>

#define N_VOX 32768
#define N_CODES 8192
#define DIM 64

// output float offsets (flat, in return order)
#define Q_OFF 0
#define VQ_OFF (N_VOX * DIM)      // 2097152
#define CM_OFF (VQ_OFF + 1)
#define IDX_OFF (VQ_OFF + 2)

// workspace float offsets
#define WS_ACC 0
#define WS_CNT 1                      // int: blocks-done counter
#define WS_ESQH 64                    // 8192 floats: -||e||^2 / 2  (NEGATED)
#define WS_IDX (WS_ESQH + N_CODES)    // (unused, layout kept)
#define WS_EHI (WS_IDX + N_VOX)       // codebook hi-plane f16 (1 MB, swizzled)
#define WS_ELO (WS_EHI + N_CODES * DIM / 2)  // lo-plane f16 (1 MB)

typedef _Float16 half8 __attribute__((ext_vector_type(8)));
typedef float floatx4 __attribute__((ext_vector_type(4)));

// async global->LDS; lds dest is wave-uniform base (+lane*size), global src per-lane
__device__ inline void gld16(const void* g, void* l) {
  __builtin_amdgcn_global_load_lds(
      (const __attribute__((address_space(1))) unsigned int*)g,
      (__attribute__((address_space(3))) unsigned int*)l, 16, 0, 0);
}

__device__ __forceinline__ floatx4 mfma16(half8 a, half8 b, floatx4 c) {
  return __builtin_amdgcn_mfma_f32_16x16x32_f16(a, b, c, 0, 0, 0);
}

// ---------------------------------------------------------------- k_cvt
// Pre-convert codebook to hi/lo f16 planes (XOR-swizzled 16B chunks) +
// NEGATED esq/2 (added at compare time; zero per-MFMA VALU).
__global__ __launch_bounds__(256) void k_cvt(const float* __restrict__ e,
                                             float* __restrict__ ws) {
  int gid = blockIdx.x * 256 + threadIdx.x;
  if (gid == 0) {                            // ws is poisoned each run
    ws[WS_ACC] = 0.f;
    ((int*)ws)[WS_CNT] = 0;
  }
  int row = gid >> 3, c = gid & 7;
  const float* src = e + (size_t)row * DIM + c * 8;
  float4 a = *(const float4*)src;
  float4 b = *(const float4*)(src + 4);
  float x[8] = {a.x, a.y, a.z, a.w, b.x, b.y, b.z, b.w};
  float s = 0.f;
  half8 hv, lv;
  #pragma unroll
  for (int j = 0; j < 8; ++j) {
    s += x[j] * x[j];                        // esq in full fp32 from originals
    _Float16 h = (_Float16)x[j];
    hv[j] = h;
    lv[j] = (_Float16)(x[j] - (float)h);
  }
  s += __shfl_xor(s, 1); s += __shfl_xor(s, 2); s += __shfl_xor(s, 4);
  if (c == 0) ws[WS_ESQH + row] = -0.5f * s;
  int p = (c + row) & 7;                     // rotate swizzle within row
  ((half8*)(ws + WS_EHI))[row * 8 + p] = hv;
  ((half8*)(ws + WS_ELO))[row * 8 + p] = lv;
}

// ---------------------------------------------------------------- k_argmin
// WAVE-PRIVATE PIPELINE: 512 blocks x 256 thr. Each wave owns a disjoint
// 2048-code range + a PRIVATE double-buffered LDS tile pair (2 x 8 KB:
// 32 codes x hi/lo, swizzled). It stages its own tiles (global_load_lds),
// self-paces with counted s_waitcnt vmcnt(10) -- NEVER 0, no __syncthreads
// in the main loop, no inter-wave coupling. Tile ct+2 staged during iter
// ct (~2 iterations = ~3700 cyc of cover); esq loads issued 1 iter ahead.
// M=4 (all 64 voxels per wave), 48 MFMA + 8 ds_read_b128 per iter.
// Score s = dot - esq/2 (maximize), esq added at compare; 3-term f16 split.
__global__ __launch_bounds__(256, 2) void k_argmin(const float* __restrict__ z,
                                                   const float* __restrict__ e,
                                                   float* __restrict__ ws,
                                                   float* __restrict__ out) {
  __shared__ __align__(16) _Float16 sB[4][2][2][2048];  // [wave][buf][hi/lo][32x64] = 64 KB
  __shared__ float sMval[4][64];
  __shared__ int   sMidx[4][64];
  __shared__ int   sWin[64];
  __shared__ float sWsum[4];

  const int tid  = threadIdx.x;
  const int lane = tid & 63;
  const int wave = tid >> 6;       // owns codes [wave*2048, wave*2048+2048)
  const int n16  = lane & 15;
  const int quad = lane >> 4;
  const int vb = blockIdx.x * 64;
  const int wcode = wave * 2048;

  const char* ehi_b = (const char*)(ws + WS_EHI);
  const char* elo_b = (const char*)(ws + WS_ELO);
  const float* esqG = ws + WS_ESQH + wcode;   // negated esq/2, this wave's range

  // A fragments: ALL 64 voxels x 64 dims, hi/lo. A[m][kc]: row=n16, k=quad*8+j
  half8 ahi[4][2], alo[4][2];
  #pragma unroll
  for (int m = 0; m < 4; ++m)
    #pragma unroll
    for (int kc = 0; kc < 2; ++kc) {
      const float* src = z + (size_t)(vb + m * 16 + n16) * DIM
                       + kc * 32 + quad * 8;
      float4 a = *(const float4*)src;
      float4 b = *(const float4*)(src + 4);
      float x[8] = {a.x, a.y, a.z, a.w, b.x, b.y, b.z, b.w};
      #pragma unroll
      for (int j = 0; j < 8; ++j) {
        _Float16 h = (_Float16)x[j];
        ahi[m][kc][j] = h;
        alo[m][kc][j] = (_Float16)(x[j] - (float)h);
      }
    }
  __builtin_amdgcn_sched_barrier(0);   // pin A-loads before staging (vmcnt FIFO)

  float bmax[4][4]; int bidx[4][4];
  #pragma unroll
  for (int m = 0; m < 4; ++m)
    #pragma unroll
    for (int r = 0; r < 4; ++r) { bmax[m][r] = -FLT_MAX; bidx[m][r] = 0; }

  // swizzled chunk offsets (f16 units); LDS row % 8 == n16 % 8
  const int s0 = ((quad + n16) & 7) * 8;          // kc=0 chunk
  const int s1 = ((quad + 4 + n16) & 7) * 8;      // kc=1 chunk

  // stage this wave's 32-code tile ct into private buffer buf: 8 gld16 ops
  auto stagew = [&](int buf, int ct) {
    const size_t gb = (size_t)(wcode + ct * 32) * 128;   // tile byte offset
    char* dH = (char*)&sB[wave][buf][0][0];
    char* dL = (char*)&sB[wave][buf][1][0];
    #pragma unroll
    for (int r = 0; r < 4; ++r) {
      gld16(ehi_b + gb + r * 1024 + lane * 16, dH + r * 1024);
      gld16(elo_b + gb + r * 1024 + lane * 16, dL + r * 1024);
    }
  };

  // prologue -- issue order pinned: STAGE(0)[8], esq_0[2], STAGE(1)[8]
  stagew(0, 0);
  __builtin_amdgcn_sched_barrier(0);
  float nqA0 = esqG[n16];
  float nqA1 = esqG[16 + n16];
  __builtin_amdgcn_sched_barrier(0);
  stagew(1, 1);
  __builtin_amdgcn_sched_barrier(0);
  float nqB0 = 0.f, nqB1 = 0.f;

  // Per iter CT: [wait vmcnt: STAGE(CT) done] [8 ds_read + esq_{CT+1} issue]
  // [lgkmcnt(0)] [STAGE(CT+2) issue] [48 MFMA + compare (uses esq_CT)]
  // FIFO after STAGE(CT): esq_CT(2) + STAGE(CT+1)(8) = 10  ->  vmcnt(10).
  // Tail: after STAGE(63): esq_63(2) only -> vmcnt(2) at CT=63.
#define ITER(CT, CUR, NQ0, NQ1, NQN0, NQN1)                                   \
  {                                                                           \
    if ((CT) < 63) { asm volatile("s_waitcnt vmcnt(10)" ::: "memory"); }      \
    else           { asm volatile("s_waitcnt vmcnt(2)"  ::: "memory"); }      \
    __builtin_amdgcn_sched_barrier(0);                                        \
    const _Float16* bp = &sB[wave][CUR][0][0];                                \
    const _Float16* lp = &sB[wave][CUR][1][0];                                \
    half8 bh00 = *(const half8*)&bp[n16 * 64 + s0];                           \
    half8 bh01 = *(const half8*)&bp[n16 * 64 + s1];                           \
    half8 bh10 = *(const half8*)&bp[(16 + n16) * 64 + s0];                    \
    half8 bh11 = *(const half8*)&bp[(16 + n16) * 64 + s1];                    \
    half8 bl00 = *(const half8*)&lp[n16 * 64 + s0];                           \
    half8 bl01 = *(const half8*)&lp[n16 * 64 + s1];                           \
    half8 bl10 = *(const half8*)&lp[(16 + n16) * 64 + s0];                    \
    half8 bl11 = *(const half8*)&lp[(16 + n16) * 64 + s1];                    \
    if ((CT) + 1 < 64) {                                                      \
      NQN0 = esqG[((CT) + 1) * 32 + n16];                                     \
      NQN1 = esqG[((CT) + 1) * 32 + 16 + n16];                                \
    }                                                                         \
    asm volatile("s_waitcnt lgkmcnt(0)" ::: "memory");                        \
    __builtin_amdgcn_sched_barrier(0);                                        \
    if ((CT) + 2 < 64) stagew(CUR, (CT) + 2);                                 \
    __builtin_amdgcn_sched_barrier(0);                                        \
    const int code0 = wcode + (CT) * 32 + n16;                                \
    __builtin_amdgcn_s_setprio(1);                                            \
    _Pragma("unroll")                                                         \
    for (int m = 0; m < 4; ++m) {                                             \
      floatx4 a0 = {0.f, 0.f, 0.f, 0.f};                                      \
      floatx4 a1 = {0.f, 0.f, 0.f, 0.f};                                      \
      a0 = mfma16(ahi[m][0], bh00, a0);  a1 = mfma16(ahi[m][1], bh01, a1);    \
      a0 = mfma16(ahi[m][0], bl00, a0);  a1 = mfma16(ahi[m][1], bl01, a1);    \
      a0 = mfma16(alo[m][0], bh00, a0);  a1 = mfma16(alo[m][1], bh01, a1);    \
      floatx4 c0 = {0.f, 0.f, 0.f, 0.f};                                      \
      floatx4 c1 = {0.f, 0.f, 0.f, 0.f};                                      \
      c0 = mfma16(ahi[m][0], bh10, c0);  c1 = mfma16(ahi[m][1], bh11, c1);    \
      c0 = mfma16(ahi[m][0], bl10, c0);  c1 = mfma16(ahi[m][1], bl11, c1);    \
      c0 = mfma16(alo[m][0], bh10, c0);  c1 = mfma16(alo[m][1], bh11, c1);    \
      _Pragma("unroll")                                                       \
      for (int r = 0; r < 4; ++r) {                                           \
        float t0 = a0[r] + a1[r] + (NQ0);                                     \
        float t1 = c0[r] + c1[r] + (NQ1);                                     \
        if (t0 > bmax[m][r]) { bmax[m][r] = t0; bidx[m][r] = code0; }         \
        if (t1 > bmax[m][r]) { bmax[m][r] = t1; bidx[m][r] = code0 + 16; }    \
      }                                                                       \
    }                                                                         \
    __builtin_amdgcn_s_setprio(0);                                            \
  }

  for (int ct2 = 0; ct2 < 64; ct2 += 2) {
    ITER(ct2,     0, nqA0, nqA1, nqB0, nqB1);
    ITER(ct2 + 1, 1, nqB0, nqB1, nqA0, nqA1);
  }
#undef ITER

  // reduce across the 16 lanes (n16 = code col) holding each voxel's partials
  #pragma unroll
  for (int m = 0; m < 4; ++m)
    #pragma unroll
    for (int r = 0; r < 4; ++r) {
      float v = bmax[m][r]; int i = bidx[m][r];
      #pragma unroll
      for (int off = 1; off < 16; off <<= 1) {
        float ov = __shfl_xor(v, off);
        int   oi = __shfl_xor(i, off);
        if (ov > v || (ov == v && oi < i)) { v = ov; i = oi; }
      }
      if (n16 == 0) {
        sMval[wave][m * 16 + quad * 4 + r] = v;
        sMidx[wave][m * 16 + quad * 4 + r] = i;
      }
    }
  __syncthreads();

  // merge the four code-quarters, publish winner index
  if (tid < 64) {
    float v = sMval[0][tid]; int i = sMidx[0][tid];
    #pragma unroll
    for (int q = 1; q < 4; ++q) {
      float ov = sMval[q][tid]; int oi = sMidx[q][tid];
      if (ov > v || (ov == v && oi < i)) { v = ov; i = oi; }
    }
    sWin[tid] = i;
    out[IDX_OFF + vb + tid] = (float)i;
  }
  __syncthreads();

  // fused k_out: gather quantized rows (exact fp32), accumulate (z-q)^2
  {
    const int vox = tid >> 2;
    const int dc = (tid & 3) * 16;
    const int gi = sWin[vox];
    const float* er = e + (size_t)gi * DIM + dc;
    const float* zr = z + (size_t)(vb + vox) * DIM + dc;
    float* qr = out + Q_OFF + (size_t)(vb + vox) * DIM + dc;
    float local = 0.f;
    #pragma unroll
    for (int j = 0; j < 4; ++j) {
      float4 e4 = *(const float4*)(er + j * 4);
      float4 z4 = *(const float4*)(zr + j * 4);
      *(float4*)(qr + j * 4) = e4;
      float dx = z4.x - e4.x, dy = z4.y - e4.y, dz = z4.z - e4.z, dw = z4.w - e4.w;
      local += dx * dx + dy * dy + dz * dz + dw * dw;
    }
    #pragma unroll
    for (int off = 32; off; off >>= 1) local += __shfl_xor(local, off);
    if ((tid & 63) == 0) sWsum[wave] = local;
    __syncthreads();
    if (tid == 0) {
      float bs = sWsum[0] + sWsum[1] + sWsum[2] + sWsum[3];
      atomicAdd(ws + WS_ACC, bs);            // device-scope
      __threadfence();
      int done = atomicAdd((int*)ws + WS_CNT, 1);
      if (done == (int)gridDim.x - 1) {      // last block: finalize scalars
        float s = atomicAdd(ws + WS_ACC, 0.f);   // atomic read (coherent)
        float mv = s * (1.0f / (float)(N_VOX * DIM));
        out[VQ_OFF] = mv;   // vq_loss
        out[CM_OFF] = mv;   // commitment_loss (identical forward value)
      }
    }
  }
}

// ----------------------------------------------------------------
extern "C" void kernel_launch(void* const* d_in, const int* in_sizes, int n_in,
                              void* d_out, int out_size, void* d_ws, size_t ws_size,
                              hipStream_t stream) {
  const float* z = (const float*)d_in[0];
  const float* e = (const float*)d_in[1];
  float* out = (float*)d_out;
  float* ws = (float*)d_ws;

  k_cvt<<<(N_CODES * 8) / 256, 256, 0, stream>>>(e, ws);
  k_argmin<<<N_VOX / 64, 256, 0, stream>>>(z, e, ws, out);
}